// Round 2
// baseline (558.702 us; speedup 1.0000x reference)
//
#include <hip/hip_runtime.h>

// Problem constants (from reference): BS=16384, DEMO_DIM=32, FEAT_DIM=256
// out[b,i,f] = x[b,i] * W[i,f] + b[i,f]   (all fp32)
// Memory-bound: 512 MiB write, ~2 MiB read. Target ~85-140 us.
//
// R1 change vs 550.3us baseline: nontemporal store -> PLAIN store.
// Theory: nt bypasses L2 allocation, so 16B per-lane stores lose L2
// write-combining into full 64B+ HBM bursts (~25% bus efficiency ~ 1.6 TB/s,
// matching the observed 0.98 TB/s). Plain stores stream through L2 with
// full-line eviction -> full-width HBM bursts.

#define BS_N      16384
#define DEMO_DIM  32
#define FEAT_DIM  256

typedef float vf4 __attribute__((ext_vector_type(4)));

__global__ __launch_bounds__(256) void demoproj_kernel(
    const float* __restrict__ x,   // (BS, DEMO_DIM)
    const float* __restrict__ W,   // (DEMO_DIM, FEAT_DIM)
    const float* __restrict__ B,   // (DEMO_DIM, FEAT_DIM)
    float* __restrict__ out)       // (BS, DEMO_DIM, FEAT_DIM)
{
    // One vf4 of output per thread. f-row is 256 floats = 64 vf4s,
    // so a 64-lane wave covers exactly one (b,i) row: x/W/B accesses are
    // wave-uniform-row -> broadcast from L1/L2.
    const size_t g = (size_t)blockIdx.x * blockDim.x + threadIdx.x;
    const size_t e = g << 2;                 // element index of first float
    const int    f = (int)(e & (FEAT_DIM - 1));
    const size_t row = e >> 8;               // = b*DEMO_DIM + i
    const int    i = (int)(row & (DEMO_DIM - 1));

    const float xv = x[row];

    const vf4 wv = *reinterpret_cast<const vf4*>(W + (size_t)i * FEAT_DIM + f);
    const vf4 bv = *reinterpret_cast<const vf4*>(B + (size_t)i * FEAT_DIM + f);

    vf4 o;
    o.x = fmaf(xv, wv.x, bv.x);
    o.y = fmaf(xv, wv.y, bv.y);
    o.z = fmaf(xv, wv.z, bv.z);
    o.w = fmaf(xv, wv.w, bv.w);

    // R1: plain store (was __builtin_nontemporal_store). Output streams
    // through L2; full-line eviction gives full-width HBM bursts.
    reinterpret_cast<vf4*>(out)[g] = o;
}

extern "C" void kernel_launch(void* const* d_in, const int* in_sizes, int n_in,
                              void* d_out, int out_size, void* d_ws, size_t ws_size,
                              hipStream_t stream) {
    const float* x = (const float*)d_in[0];
    const float* W = (const float*)d_in[1];
    const float* B = (const float*)d_in[2];
    float* out = (float*)d_out;

    // total vf4s = BS*DEMO_DIM*FEAT_DIM / 4 = 33,554,432
    const size_t total_f4 = (size_t)BS_N * DEMO_DIM * FEAT_DIM / 4;
    const int block = 256;
    const int grid = (int)(total_f4 / block);   // 131072, exact

    demoproj_kernel<<<grid, block, 0, stream>>>(x, W, B, out);
}

// Round 4
// 545.507 us; speedup vs baseline: 1.0242x; 1.0242x over previous
//
#include <hip/hip_runtime.h>

// Problem: out[b,i,f] = x[b,i] * W[i,f] + b[i,f]   (all fp32)
// BS=16384, DEMO_DIM=32, FEAT_DIM=256. 512 MiB write / ~2 MiB read.
//
// R2 redesign: fill-shaped grid-stride kernel.
// Evidence: harness fillBufferAligned reaches 6.3 TB/s (78% peak) at 10%
// occupancy with a grid-stride store stream; our one-store-per-wave kernel
// managed only ~1 TB/s (558 us) regardless of store flavor (R1 A/B).
// Diagnosis: per-wave fixed cost (kernarg s_load ~500cy, addr setup, load
// latency with zero ILP) amortized over just 1 KiB of payload, x524288 waves.
// Fix: 8192 waves, each streaming 64 independent 1 KiB stores.
//   rows r = wv + k*8192. 8192 % 32 == 0  =>  i = r & 31 is WAVE-CONSTANT:
//   W/B fragments load once into registers; inner loop = uniform x[r] load
//   + 4 FMA + 1 global_store_dwordx4 (fire-and-forget).

#define BS_N      16384
#define DEMO_DIM  32
#define FEAT_DIM  256
#define NROWS     (BS_N * DEMO_DIM)      // 524288 output rows of 256 floats
#define NBLOCKS   2048
#define NWAVES    (NBLOCKS * 4)          // 8192
#define ITERS     (NROWS / NWAVES)       // 64, exact

typedef float vf4 __attribute__((ext_vector_type(4)));

__global__ __launch_bounds__(256) void demoproj_kernel(
    const float* __restrict__ x,   // (BS, DEMO_DIM)
    const float* __restrict__ W,   // (DEMO_DIM, FEAT_DIM)
    const float* __restrict__ B,   // (DEMO_DIM, FEAT_DIM)
    float* __restrict__ out)       // (BS, DEMO_DIM, FEAT_DIM)
{
    const int lane = threadIdx.x & 63;
    const int wv   = blockIdx.x * 4 + (threadIdx.x >> 6);  // 0..8191
    const int f    = lane << 2;                            // 0,4,...,252
    const int i    = wv & (DEMO_DIM - 1);                  // wave-constant

    // Per-wave-constant W/B fragments: loaded once, live in 8 VGPRs.
    const vf4 wreg = *reinterpret_cast<const vf4*>(W + (size_t)i * FEAT_DIM + f);
    const vf4 breg = *reinterpret_cast<const vf4*>(B + (size_t)i * FEAT_DIM + f);

    // Each wave streams 64 rows, stride NWAVES rows (= 8 MiB in out).
    size_t r = (size_t)wv;
    float* o0 = out + (size_t)wv * FEAT_DIM + f;
    const size_t ostride = (size_t)NWAVES * FEAT_DIM;      // floats per iter

    #pragma unroll 4
    for (int k = 0; k < ITERS; ++k, r += NWAVES, o0 += ostride) {
        const float xv = x[r];                 // wave-uniform scalar load
        vf4 o;
        o.x = fmaf(xv, wreg.x, breg.x);
        o.y = fmaf(xv, wreg.y, breg.y);
        o.z = fmaf(xv, wreg.z, breg.z);
        o.w = fmaf(xv, wreg.w, breg.w);
        *reinterpret_cast<vf4*>(o0) = o;       // independent 1 KiB/wave store
    }
}

extern "C" void kernel_launch(void* const* d_in, const int* in_sizes, int n_in,
                              void* d_out, int out_size, void* d_ws, size_t ws_size,
                              hipStream_t stream) {
    const float* x = (const float*)d_in[0];
    const float* W = (const float*)d_in[1];
    const float* B = (const float*)d_in[2];
    float* out = (float*)d_out;

    demoproj_kernel<<<NBLOCKS, 256, 0, stream>>>(x, W, B, out);
}

// Round 8
// 540.672 us; speedup vs baseline: 1.0333x; 1.0089x over previous
//
#include <hip/hip_runtime.h>

// Problem: out[b,i,f] = x[b,i] * W[i,f] + b[i,f]   (all fp32)
// BS=16384, DEMO_DIM=32, FEAT_DIM=256. 512 MiB write / ~2 MiB read.
//
// R4: pure-store-stream kernel (discriminating experiment).
// Evidence so far: our kernel never appears in rocprof top-5 (all slots are
// 2GiB poison-fills at ~340us, 6.3 TB/s), so kernel dispatch < 336us and the
// ~545us headline = fixed harness component + kernel. R2's grid-stride
// redesign moved the headline only -13us, so either the kernel is stuck at
// ~2.6 TB/s (per-iter dependent x-load chain) or it is already ~90us and the
// headline is harness floor.
// This version removes the LAST per-iteration memory dependence:
//   - W/B fragments: wave-constant (8192 % 32 == 0), hoisted to 8 VGPRs.
//   - x: ONE lane-parallel gather up front (lane k holds x[wv + k*8192]),
//     iteration k broadcasts it via v_readlane (register-only).
//   - inner loop = readlane + 4 FMA + 1 independent global_store_dwordx4.
// Structurally identical to the 6.3 TB/s fill. If headline drops to ~430us,
// the x-chain was the bottleneck; if unchanged, kernel was already at the
// write roofline and the residual is harness-side.

#define BS_N      16384
#define DEMO_DIM  32
#define FEAT_DIM  256
#define NROWS     (BS_N * DEMO_DIM)      // 524288 output rows of 256 floats
#define NBLOCKS   2048
#define NWAVES    (NBLOCKS * 4)          // 8192 waves = 32/CU (max occupancy)
#define ITERS     (NROWS / NWAVES)       // 64, exact

typedef float vf4 __attribute__((ext_vector_type(4)));

__global__ __launch_bounds__(256) void demoproj_kernel(
    const float* __restrict__ x,   // (BS, DEMO_DIM)
    const float* __restrict__ W,   // (DEMO_DIM, FEAT_DIM)
    const float* __restrict__ B,   // (DEMO_DIM, FEAT_DIM)
    float* __restrict__ out)       // (BS, DEMO_DIM, FEAT_DIM)
{
    const int lane = threadIdx.x & 63;
    const int wv   = blockIdx.x * 4 + (threadIdx.x >> 6);  // 0..8191
    const int f    = lane << 2;                            // 0,4,...,252
    const int i    = wv & (DEMO_DIM - 1);                  // wave-constant

    // Wave-constant W/B fragments: loaded once, live in 8 VGPRs.
    const vf4 wreg = *reinterpret_cast<const vf4*>(W + (size_t)i * FEAT_DIM + f);
    const vf4 breg = *reinterpret_cast<const vf4*>(B + (size_t)i * FEAT_DIM + f);

    // Prefetch ALL 64 x-values this wave needs with ONE gather:
    // lane k holds x for iteration k (row wv + k*NWAVES).
    const float xlane = x[(size_t)wv + (size_t)lane * NWAVES];

    float* o0 = out + (size_t)wv * FEAT_DIM + f;
    const size_t ostride = (size_t)NWAVES * FEAT_DIM;      // floats per iter

    #pragma unroll 8
    for (int k = 0; k < ITERS; ++k, o0 += ostride) {
        // Broadcast lane k's x value to all lanes: register-only, no memory.
        const float xv = __uint_as_float(
            __builtin_amdgcn_readlane(__float_as_uint(xlane), k));
        vf4 o;
        o.x = fmaf(xv, wreg.x, breg.x);
        o.y = fmaf(xv, wreg.y, breg.y);
        o.z = fmaf(xv, wreg.z, breg.z);
        o.w = fmaf(xv, wreg.w, breg.w);
        *reinterpret_cast<vf4*>(o0) = o;   // independent 1 KiB/wave store
    }
}

extern "C" void kernel_launch(void* const* d_in, const int* in_sizes, int n_in,
                              void* d_out, int out_size, void* d_ws, size_t ws_size,
                              hipStream_t stream) {
    const float* x = (const float*)d_in[0];
    const float* W = (const float*)d_in[1];
    const float* B = (const float*)d_in[2];
    float* out = (float*)d_out;

    demoproj_kernel<<<NBLOCKS, 256, 0, stream>>>(x, W, B, out);
}